// Round 1
// baseline (422.474 us; speedup 1.0000x reference)
//
#include <hip/hip_runtime.h>
#include <math.h>

// GNO layer: out[i] = mean_k( GELU( [coords[j]-coords[i], feat[j]] @ W1 + b1 ) ) @ W2 + b2
//            + feat[i] @ Ws + bs,   j = idx[i][k], K=16, C=64.
//
// Algebraic refactor:
//   G[j]  = feat[j] @ W1[3:67] + b1              (phase 1, N x 64x64 matvec)
//   hbar_i = (1/K) sum_k GELU( rel_ik @ W1[0:3] + G[idx[i][k]] )
//   out[i] = hbar_i @ W2 + b2 + feat[i] @ Ws + bs (phase 2)

#define NPTS_K 16

__global__ __launch_bounds__(256, 4) void gno_phase1(
    const float* __restrict__ features, const float* __restrict__ W1,
    const float* __restrict__ b1, float* __restrict__ G, int n)
{
    __shared__ float w1s[64 * 64];
    __shared__ float b1s[64];
    __shared__ float fs[4 * 64];
    const int tid = threadIdx.y * 64 + threadIdx.x;
    for (int t = tid; t < 64 * 64; t += 256) w1s[t] = W1[3 * 64 + t];  // rows 3..66
    if (tid < 64) b1s[tid] = b1[tid];
    __syncthreads();

    const int c = threadIdx.x;
    const int y = threadIdx.y;
    const int P = gridDim.x * 4;
    const int iters = (n + P - 1) / P;
    for (int it = 0; it < iters; ++it) {
        const int j = it * P + blockIdx.x * 4 + y;
        if (j < n) {
            // coalesced load of the feature row into wave-private LDS slice
            fs[y * 64 + c] = features[(size_t)j * 64 + c];
            float acc = b1s[c];
            #pragma unroll
            for (int d = 0; d < 64; ++d)
                acc = fmaf(fs[y * 64 + d], w1s[d * 64 + c], acc);
            G[(size_t)j * 64 + c] = acc;
        }
    }
}

__global__ __launch_bounds__(256, 4) void gno_phase2(
    const float* __restrict__ coords, const float* __restrict__ features,
    const int* __restrict__ idx, const float* __restrict__ W1,
    const float* __restrict__ W2, const float* __restrict__ b2,
    const float* __restrict__ Ws, const float* __restrict__ bs,
    const float* __restrict__ G, float* __restrict__ out, int n)
{
    __shared__ float w1p[3 * 64];   // rel-pos rows of W1
    __shared__ float w2s[64 * 64];
    __shared__ float wss[64 * 64];
    __shared__ float b2s[64], bss[64];
    __shared__ float hs[4 * 64];
    __shared__ float fs2[4 * 64];

    const int tid = threadIdx.y * 64 + threadIdx.x;
    for (int t = tid; t < 64 * 64; t += 256) { w2s[t] = W2[t]; wss[t] = Ws[t]; }
    for (int t = tid; t < 3 * 64; t += 256) w1p[t] = W1[t];
    if (tid < 64) { b2s[tid] = b2[tid]; bss[tid] = bs[tid]; }
    __syncthreads();

    const int c = threadIdx.x;
    const int y = threadIdx.y;
    const int P = gridDim.x * 4;
    const int iters = (n + P - 1) / P;
    for (int it = 0; it < iters; ++it) {
        const int i = it * P + blockIdx.x * 4 + y;
        if (i < n) {
            const float cx = coords[(size_t)i * 3 + 0];
            const float cy = coords[(size_t)i * 3 + 1];
            const float cz = coords[(size_t)i * 3 + 2];
            // stage this point's feature row (coalesced) for the epilogue matvec
            fs2[y * 64 + c] = features[(size_t)i * 64 + c];

            float acc = 0.f;
            #pragma unroll
            for (int k = 0; k < NPTS_K; ++k) {
                const int j = idx[i * NPTS_K + k];
                const float rx = coords[(size_t)j * 3 + 0] - cx;
                const float ry = coords[(size_t)j * 3 + 1] - cy;
                const float rz = coords[(size_t)j * 3 + 2] - cz;
                float pre = G[(size_t)j * 64 + c];          // coalesced 256B gather
                pre = fmaf(rx, w1p[c], pre);
                pre = fmaf(ry, w1p[64 + c], pre);
                pre = fmaf(rz, w1p[128 + c], pre);
                // exact GELU (erf form, matches torch/jax approximate=False)
                acc += 0.5f * pre * (1.0f + erff(pre * 0.70710678118654752f));
            }
            acc *= (1.0f / NPTS_K);
            hs[y * 64 + c] = acc;   // wave-private slice; wave64 lockstep ordering

            float o = b2s[c] + bss[c];
            #pragma unroll
            for (int d = 0; d < 64; ++d) {
                o = fmaf(hs[y * 64 + d], w2s[d * 64 + c], o);
                o = fmaf(fs2[y * 64 + d], wss[d * 64 + c], o);
            }
            out[(size_t)i * 64 + c] = o;
        }
    }
}

extern "C" void kernel_launch(void* const* d_in, const int* in_sizes, int n_in,
                              void* d_out, int out_size, void* d_ws, size_t ws_size,
                              hipStream_t stream) {
    const float* coords   = (const float*)d_in[0];
    const float* features = (const float*)d_in[1];
    const int*   idx      = (const int*)d_in[2];
    const float* W1       = (const float*)d_in[3];
    const float* b1       = (const float*)d_in[4];
    const float* W2       = (const float*)d_in[5];
    const float* b2       = (const float*)d_in[6];
    const float* Ws       = (const float*)d_in[7];
    const float* bs       = (const float*)d_in[8];
    float* out = (float*)d_out;
    const int n = in_sizes[0] / 3;            // 100000
    float* G = (float*)d_ws;                  // n*64 floats = 25.6 MB

    dim3 block(64, 4);
    dim3 grid(2048);
    gno_phase1<<<grid, block, 0, stream>>>(features, W1, b1, G, n);
    gno_phase2<<<grid, block, 0, stream>>>(coords, features, idx, W1, W2, b2,
                                           Ws, bs, G, out, n);
}